// Round 1
// baseline (294.007 us; speedup 1.0000x reference)
//
#include <hip/hip_runtime.h>
#include <math.h>

// BoundaryFocalLoss: B=128, T=200000, f32 inputs, i32 targets, f32 mask -> scalar f32.
// ~307 MB footprint; L3 serves ~half (FETCH ~152 MB).
//
// R1: 654 us = same-address atomic serialization -> partials + 2nd kernel (124 us).
// R2: latency-bound (16% HBM, 4 blocks/CU). R3: 2560 blocks -> 119 us, VGPR=28.
// R4: 64-VGPR cap -> register arrays spilled to scratch -> 228 us. NEVER cap below working set.
// R5: named-register Chunk double-buffer + prefetch pipeline -> 118 us. Counters:
//     VALUBusy 30%, HBM 16%, Occupancy 18.7%, VGPR=120 (4 waves/SIMD). Latency-bound:
//     neither pipe near ceiling; the staging working set IS the registers.
// R6 (this): move staging out of VGPRs -> global_load_lds DMA into PER-WAVE-PRIVATE
//     LDS double buffers. No barriers in the main loop (per-wave pacing via counted
//     s_waitcnt vmcnt(4)); targets' neighbor window read straight from the staged LDS
//     tile (only the 2 tile-edge groups need a predicated global load). LDS 24.6 KB/block
//     -> 6 blocks/CU resident; grid 12x128 = 1536 blocks = exact resident capacity.

#define B_DIM 128
#define T_DIM 200000

constexpr int BLOCK        = 256;
constexpr int WPB          = 4;                         // waves per block
constexpr int BLOCKS_X     = 12;                        // 12*128 = 1536 blocks (6/CU * 256 CU)
constexpr int WAVES_ROW    = BLOCKS_X * WPB;            // 48 waves sweep one row
constexpr int GROUPS_ROW   = T_DIM / 4;                 // 50000 float4/int4 groups
constexpr int LAST_G       = GROUPS_ROW - 1;            // 49999
constexpr int NTILES       = (GROUPS_ROW + 63) / 64;    // 782 (tile 781 partial: 16 groups)
constexpr int NIT          = (NTILES + WAVES_ROW - 1) / WAVES_ROW;  // 17 stages/wave
constexpr int NUM_PARTIALS = BLOCKS_X * B_DIM;          // 1536

// Per-wave LDS: x[2][1024B] @ +0, m[2][1024B] @ +2048, t[2][1024B] @ +4096
constexpr int WBYTES = 6144;

__device__ __forceinline__ void async16(void* lds, const void* g) {
    typedef const unsigned int __attribute__((address_space(1)))* GP;
    typedef unsigned int       __attribute__((address_space(3)))* LP;
    // HW semantics: LDS dest = wave-uniform base + lane*16; global src is per-lane.
    __builtin_amdgcn_global_load_lds((GP)g, (LP)lds, 16, 0, 0);
}

__global__ __launch_bounds__(BLOCK, 6) void bfl_main(
    const float* __restrict__ inputs,
    const int*   __restrict__ targets,
    const float* __restrict__ mask,
    float2*      __restrict__ partials)   // [NUM_PARTIALS] = (loss_sum, mask_sum)
{
    __shared__ int4  smem4[WPB * WBYTES / 16];
    __shared__ float sL[WPB];
    __shared__ float sM[WPB];

    const int b    = blockIdx.y;
    const int tid  = threadIdx.x;
    const int wid  = tid >> 6;
    const int lane = tid & 63;

    const long long row = (long long)b * T_DIM;
    const char* gx  = (const char*)(inputs  + row);
    const char* gm  = (const char*)(mask    + row);
    const char* gt  = (const char*)(targets + row);
    const int4* pt4 = (const int4*)(targets + row);

    char* wlds = (char*)smem4 + wid * WBYTES;

    const int tile0 = blockIdx.x * WPB + wid;           // [0, 48)

    float lsum = 0.0f, msum = 0.0f;
    int4 e1 = make_int4(0, 0, 0, 0);                    // incoming edge (lanes 0/63 only)

    // Issue stage 'it': 3 fire-and-forget DMAs (x,m,t -> 1 KB each) + predicated edge load.
    auto issue = [&](int it) {
        const int tb = (tile0 + it * WAVES_ROW) * 64;   // tile base group (may be OOR: clamped)
        const int g  = min(tb + lane, LAST_G);
        const int go = g * 16;
        char* dst = wlds + (it & 1) * 1024;
        async16(dst,        gx + go);
        async16(dst + 2048, gm + go);
        async16(dst + 4096, gt + go);
        if (lane == 0 || lane == 63) {
            int ge = (lane == 0) ? (tb - 1) : (tb + 64);
            ge = min(max(ge, 0), LAST_G);
            e1 = pt4[ge];                                // edge: prev group (lane0) / next group (lane63)
        }
    };

    auto compute = [&](int it, const int4 e0) {
        const char* base = wlds + (it & 1) * 1024;
        const float4 x4 = *(const float4*)(base + lane * 16);
        const float4 m4 = *(const float4*)(base + 2048 + lane * 16);
        const int4* tbuf = (const int4*)(base + 4096);
        const int4 c = tbuf[lane];
        int4 pv = tbuf[(lane == 0)  ? 0  : (lane - 1)];
        int4 nx = tbuf[(lane == 63) ? 63 : (lane + 1)];
        if (lane == 0)  pv = e0;
        if (lane == 63) nx = e0;

        const int  tb    = (tile0 + it * WAVES_ROW) * 64;
        const int  graw  = tb + lane;
        const bool valid = (graw < GROUPS_ROW);
        const float scale = valid ? 1.0f : 0.0f;
        const int  g = valid ? graw : LAST_G;

        // Row-edge replicate: makes out-of-row transition bits compare-equal -> 0,
        // matching reference's zero-padded trans[0] and 'SAME' window clipping.
        if (g == 0)      { pv.x = c.x; pv.y = c.x; pv.z = c.x; pv.w = c.x; }
        if (g == LAST_G) { nx.x = c.w; nx.y = c.w; nx.z = c.w; }

        // transition bits: bit k <-> trans at relative position r = k-3 (r=0 is elem 0)
        unsigned mb = 0u;
        mb |= (pv.y != pv.x) ? 0x001u : 0u;
        mb |= (pv.z != pv.y) ? 0x002u : 0u;
        mb |= (pv.w != pv.z) ? 0x004u : 0u;
        mb |= (c.x  != pv.w) ? 0x008u : 0u;
        mb |= (c.y  != c.x ) ? 0x010u : 0u;
        mb |= (c.z  != c.y ) ? 0x020u : 0u;
        mb |= (c.w  != c.z ) ? 0x040u : 0u;
        mb |= (nx.x != c.w ) ? 0x080u : 0u;
        mb |= (nx.y != nx.x) ? 0x100u : 0u;
        mb |= (nx.z != nx.y) ? 0x200u : 0u;
        // window-OR over 7 bits: o bit i = OR(mb[i..i+6]) = boundary of elem i
        unsigned o = mb | (mb >> 1);
        o |= o >> 2;
        o |= o >> 3;

        auto elem = [&](float x, float mraw, int t, unsigned bit) {
            const float mm   = mraw * scale;
            const float posf = (float)t;                         // targets in {0,1}

            const float smoothed = fmaf(posf, 0.95f, 0.025f);    // pos*(1-ls)+ls/2
            const float alpha_w  = fmaf(posf, -0.5f, 0.75f);     // 0.25 pos + 0.75 neg
            const float w        = fmaf((float)bit, 4.0f, 1.0f); // 1 or 5

            // ea = exp(-|x|); sigmoid(|x|) = 1/(1+ea); |sigmoid(x)-0.5| = sigmoid(|x|)-0.5
            const float ea   = __expf(-fabsf(x));
            const float opea = 1.0f + ea;
            const float r    = __builtin_amdgcn_rcpf(opea);
            const float adaptive = 1.5f - r;

            const float bce = fmaf(-x, smoothed, fmaxf(x, 0.0f)) + __logf(opea);
            const float pt  = __expf(-bce);
            const float om  = 1.0f - pt;

            lsum = fmaf(alpha_w * om * om * bce * w * adaptive, mm, lsum);
            msum += mm;
        };

        elem(x4.x, m4.x, c.x, (o      ) & 1u);
        elem(x4.y, m4.y, c.y, (o >> 1 ) & 1u);
        elem(x4.z, m4.z, c.z, (o >> 2 ) & 1u);
        elem(x4.w, m4.w, c.w, (o >> 3 ) & 1u);
    };

    issue(0);
    for (int it = 0; it < NIT; ++it) {
        const int4 e0 = e1;          // compiler inserts the wait for stage-it's edge load,
                                     // which was issued LAST in stage it -> implies LDS DMAs done
        issue(it + 1);               // it==NIT-1 issues a clamped dummy: uniform vmcnt pattern
        // Stage it+1's 4 vmem ops are the 4 newest in flight; waiting to <=4 guarantees
        // stage it's 3 LDS DMAs + edge load have landed. Never drains the prefetch.
        asm volatile("s_waitcnt vmcnt(4)" ::: "memory");
        __builtin_amdgcn_sched_barrier(0);
        compute(it, e0);
    }

    // wave (64-lane) butterfly reduction
    #pragma unroll
    for (int off = 32; off > 0; off >>= 1) {
        lsum += __shfl_xor(lsum, off);
        msum += __shfl_xor(msum, off);
    }

    if (lane == 0) { sL[wid] = lsum; sM[wid] = msum; }
    __syncthreads();

    if (tid == 0) {
        float bl = 0.0f, bm = 0.0f;
        #pragma unroll
        for (int i = 0; i < WPB; ++i) { bl += sL[i]; bm += sM[i]; }
        partials[b * BLOCKS_X + blockIdx.x] = make_float2(bl, bm);
    }
}

__global__ __launch_bounds__(BLOCK) void bfl_reduce(
    const float2* __restrict__ partials,
    float*        __restrict__ out)
{
    float ls = 0.0f, ms = 0.0f;
    #pragma unroll
    for (int i = 0; i < NUM_PARTIALS / BLOCK; ++i) {
        const float2 p = partials[i * BLOCK + threadIdx.x];
        ls += p.x; ms += p.y;
    }

    #pragma unroll
    for (int off = 32; off > 0; off >>= 1) {
        ls += __shfl_xor(ls, off);
        ms += __shfl_xor(ms, off);
    }

    __shared__ float sL[BLOCK / 64];
    __shared__ float sM[BLOCK / 64];
    const int wave = threadIdx.x >> 6;
    const int lane = threadIdx.x & 63;
    if (lane == 0) { sL[wave] = ls; sM[wave] = ms; }
    __syncthreads();

    if (threadIdx.x == 0) {
        float bl = 0.0f, bm = 0.0f;
        #pragma unroll
        for (int i = 0; i < BLOCK / 64; ++i) { bl += sL[i]; bm += sM[i]; }
        out[0] = (bm > 0.0f) ? (bl / bm) : 0.0f;
    }
}

extern "C" void kernel_launch(void* const* d_in, const int* in_sizes, int n_in,
                              void* d_out, int out_size, void* d_ws, size_t ws_size,
                              hipStream_t stream) {
    const float* inputs   = (const float*)d_in[0];
    const int*   targets  = (const int*)d_in[1];
    const float* mask     = (const float*)d_in[2];
    float*       out      = (float*)d_out;
    float2*      partials = (float2*)d_ws;

    dim3 grid(BLOCKS_X, B_DIM);
    bfl_main<<<grid, BLOCK, 0, stream>>>(inputs, targets, mask, partials);
    bfl_reduce<<<1, BLOCK, 0, stream>>>(partials, out);
}